// Round 1
// baseline (3563.366 us; speedup 1.0000x reference)
//
#include <hip/hip_runtime.h>
#include <math.h>

#define BATCH 32768
#define NSP 26
#define NDN 13
#define VOC 10000
#define EDIM 64
#define NHEAD 2
#define DHEAD 32
#define NLAY 3
#define HID1 256
#define HID2 128
#define DIN 1677          // 13 + 26*64
#define XW 39             // NSP + NDN
#define ST 68             // LDS row stride (floats): 68*4=272B, 16B-aligned, odd mod 32 pattern

// ---------------------------------------------------------------------------
// K1: logit0[b] = relu(X[b,:] @ lin_W + lin_b)
// ---------------------------------------------------------------------------
__global__ void k_lin(const float* __restrict__ X, const float* __restrict__ lw,
                      const float* __restrict__ lb, float* __restrict__ logit0) {
    int b = blockIdx.x * 256 + threadIdx.x;
    float s = lb[0];
    const float* xr = X + (long)b * XW;
#pragma unroll
    for (int i = 0; i < XW; i++) s = fmaf(xr[i], lw[i], s);
    logit0[b] = fmaxf(s, 0.f);
}

// ---------------------------------------------------------------------------
// K2: fused 3-layer AutoInt interaction. One wave (64 lanes) per sample.
// Per-sample LDS: att[26][ST], sA[26][ST], sB[26][ST].
// Pass1: lane e computes column e of q,k,v,res (VALU, att broadcast-read).
// Pass2: lane (h,i) (52 active) computes scores row, softmax, attn@v.
// Pass3: att = relu(out + res). Finally p1[b] = att_flat @ out_W[0:1664].
// ---------------------------------------------------------------------------
__global__ __launch_bounds__(128) void k_interact(
    const int* __restrict__ sidx, const float* __restrict__ emb,
    const float* __restrict__ Wq, const float* __restrict__ Wk,
    const float* __restrict__ Wv, const float* __restrict__ Wr,
    const float* __restrict__ outW, float* __restrict__ p1)
{
    __shared__ float smem[2][3][NSP * ST];
    const int wid  = threadIdx.x >> 6;
    const int lane = threadIdx.x & 63;
    const int b    = blockIdx.x * 2 + wid;
    float* att = smem[wid][0];
    float* sA  = smem[wid][1];
    float* sB  = smem[wid][2];

    // gather embeddings -> att  (coalesced over lane=e)
#pragma unroll
    for (int f = 0; f < NSP; f++) {
        int idx = sidx[b * NSP + f];
        att[f * ST + lane] = emb[((long)f * VOC + idx) * EDIM + lane];
    }
    __syncthreads();

    const int  hh  = lane / NSP;    // head (lanes 52..63 inactive)
    const int  ii  = lane % NSP;    // query row
    const bool act = lane < 2 * NSP;

    float rc[NSP];

    for (int l = 0; l < NLAY; l++) {
        const float* wq = Wq + l * EDIM * EDIM;
        const float* wk = Wk + l * EDIM * EDIM;
        const float* wv = Wv + l * EDIM * EDIM;
        const float* wr = Wr + l * EDIM * EDIM;

        float qc[NSP], kc[NSP], vc[NSP];
#pragma unroll
        for (int f = 0; f < NSP; f++) { qc[f] = 0.f; kc[f] = 0.f; vc[f] = 0.f; rc[f] = 0.f; }

        for (int k4 = 0; k4 < EDIM / 4; k4++) {
            const int k = k4 * 4;
            float wqv[4], wkv[4], wvv[4], wrv[4];
#pragma unroll
            for (int j = 0; j < 4; j++) {
                wqv[j] = wq[(k + j) * EDIM + lane];
                wkv[j] = wk[(k + j) * EDIM + lane];
                wvv[j] = wv[(k + j) * EDIM + lane];
                wrv[j] = wr[(k + j) * EDIM + lane];
            }
#pragma unroll
            for (int f = 0; f < NSP; f++) {
                float4 a = *(const float4*)&att[f * ST + k];  // wave-broadcast LDS read
                qc[f] = fmaf(a.x, wqv[0], fmaf(a.y, wqv[1], fmaf(a.z, wqv[2], fmaf(a.w, wqv[3], qc[f]))));
                kc[f] = fmaf(a.x, wkv[0], fmaf(a.y, wkv[1], fmaf(a.z, wkv[2], fmaf(a.w, wkv[3], kc[f]))));
                vc[f] = fmaf(a.x, wvv[0], fmaf(a.y, wvv[1], fmaf(a.z, wvv[2], fmaf(a.w, wvv[3], vc[f]))));
                rc[f] = fmaf(a.x, wrv[0], fmaf(a.y, wrv[1], fmaf(a.z, wrv[2], fmaf(a.w, wrv[3], rc[f]))));
            }
        }
        __syncthreads();

        // q -> sA, k -> sB, v -> att (old att fully consumed above)
#pragma unroll
        for (int f = 0; f < NSP; f++) {
            sA[f * ST + lane]  = qc[f];
            sB[f * ST + lane]  = kc[f];
            att[f * ST + lane] = vc[f];
        }
        __syncthreads();

        float attn[NSP];
        float inv = 0.f;
        if (act) {
            float qrow[DHEAD];
#pragma unroll
            for (int d4 = 0; d4 < DHEAD / 4; d4++) {
                float4 q4 = *(const float4*)&sA[ii * ST + hh * DHEAD + d4 * 4];
                qrow[d4*4+0] = q4.x; qrow[d4*4+1] = q4.y; qrow[d4*4+2] = q4.z; qrow[d4*4+3] = q4.w;
            }
            float mx = -1e30f;
#pragma unroll
            for (int j = 0; j < NSP; j++) {
                float s = 0.f;
#pragma unroll
                for (int d4 = 0; d4 < DHEAD / 4; d4++) {
                    float4 k4v = *(const float4*)&sB[j * ST + hh * DHEAD + d4 * 4];
                    s = fmaf(qrow[d4*4+0], k4v.x, fmaf(qrow[d4*4+1], k4v.y,
                        fmaf(qrow[d4*4+2], k4v.z, fmaf(qrow[d4*4+3], k4v.w, s))));
                }
                attn[j] = s;
                mx = fmaxf(mx, s);
            }
            float sum = 0.f;
#pragma unroll
            for (int j = 0; j < NSP; j++) { attn[j] = __expf(attn[j] - mx); sum += attn[j]; }
            inv = 1.f / sum;
        }
        __syncthreads();

        if (act) {
            float o[DHEAD];
#pragma unroll
            for (int d = 0; d < DHEAD; d++) o[d] = 0.f;
#pragma unroll
            for (int j = 0; j < NSP; j++) {
                float a = attn[j] * inv;
#pragma unroll
                for (int d4 = 0; d4 < DHEAD / 4; d4++) {
                    float4 v4 = *(const float4*)&att[j * ST + hh * DHEAD + d4 * 4];
                    o[d4*4+0] = fmaf(a, v4.x, o[d4*4+0]);
                    o[d4*4+1] = fmaf(a, v4.y, o[d4*4+1]);
                    o[d4*4+2] = fmaf(a, v4.z, o[d4*4+2]);
                    o[d4*4+3] = fmaf(a, v4.w, o[d4*4+3]);
                }
            }
            // out -> sB (k-tiles dead)
#pragma unroll
            for (int d4 = 0; d4 < DHEAD / 4; d4++) {
                float4 ov = make_float4(o[d4*4+0], o[d4*4+1], o[d4*4+2], o[d4*4+3]);
                *(float4*)&sB[ii * ST + hh * DHEAD + d4 * 4] = ov;
            }
        }
        __syncthreads();

        // att = relu(out + res)
#pragma unroll
        for (int f = 0; f < NSP; f++)
            att[f * ST + lane] = fmaxf(sB[f * ST + lane] + rc[f], 0.f);
        __syncthreads();
    }

    // p1[b] = att_flat @ out_W[0:1664]
    float s = 0.f;
#pragma unroll
    for (int f = 0; f < NSP; f++) s = fmaf(att[f * ST + lane], outW[f * EDIM + lane], s);
#pragma unroll
    for (int off = 32; off > 0; off >>= 1) s += __shfl_down(s, off);
    if (lane == 0) p1[b] = s;
}

// ---------------------------------------------------------------------------
// K3: fused DNN + final. Block = 256 threads handles 32 samples.
// GEMM1 (32 x 1677 @ 1677 x 256) tiled fp32 -> h1 in LDS -> h2 -> p2 ->
// out[b] = sigmoid(logit0 + p1 + p2).  dnn_in re-gathered from emb tables.
// ---------------------------------------------------------------------------
__global__ __launch_bounds__(256) void k_dnn(
    const float* __restrict__ X, const int* __restrict__ sidx,
    const float* __restrict__ emb, const float* __restrict__ W1,
    const float* __restrict__ b1, const float* __restrict__ W2,
    const float* __restrict__ b2, const float* __restrict__ outW,
    const float* __restrict__ logit0, const float* __restrict__ p1,
    float* __restrict__ out)
{
    __shared__ float smem[640 + 4608 + 8192];       // 53760 B
    float* A   = smem;                  // [32][20]  A-tile (padded, 16B-aligned rows)
    float* BT  = smem + 640;            // [256][18] W1 chunk, transposed
    float* h1  = smem + 640 + 4608;     // [32][256]
    float* h2b = smem;                  // alias A/BT after GEMM1: [32][129]

    const int t  = threadIdx.x;
    const int bM = blockIdx.x * 32;
    const int tx = t & 31, ty = t >> 5;

    float acc[4][8];
#pragma unroll
    for (int i = 0; i < 4; i++)
#pragma unroll
        for (int j = 0; j < 8; j++) acc[i][j] = 0.f;

    for (int ch = 0; ch < (DIN + 15) / 16; ch++) {
        const int k0 = ch * 16;
        // stage A: dnn_in[bM..bM+31][k0..k0+15]
        for (int e = t; e < 512; e += 256) {
            int kk = e & 15, r = e >> 4;
            int k = k0 + kk;
            float v = 0.f;
            if (k < DIN) {
                int bb = bM + r;
                if (k < NDN) v = X[(long)bb * XW + NSP + k];
                else {
                    int km = k - NDN;
                    int f = km >> 6, ee = km & 63;
                    v = emb[((long)f * VOC + sidx[bb * NSP + f]) * EDIM + ee];
                }
            }
            A[r * 20 + kk] = v;
        }
        // stage BT: W1[k0..k0+15][0..255] transposed
        for (int e = t; e < 4096; e += 256) {
            int c = e & 255, kk = e >> 8;
            int k = k0 + kk;
            BT[c * 18 + kk] = (k < DIN) ? W1[(long)k * HID1 + c] : 0.f;
        }
        __syncthreads();
#pragma unroll
        for (int kk2 = 0; kk2 < 8; kk2++) {
            float2 bv[8], av[4];
#pragma unroll
            for (int j = 0; j < 8; j++) bv[j] = *(const float2*)&BT[(tx + 32 * j) * 18 + kk2 * 2];
#pragma unroll
            for (int i = 0; i < 4; i++) av[i] = *(const float2*)&A[(ty + 8 * i) * 20 + kk2 * 2];
#pragma unroll
            for (int i = 0; i < 4; i++)
#pragma unroll
                for (int j = 0; j < 8; j++)
                    acc[i][j] = fmaf(av[i].x, bv[j].x, fmaf(av[i].y, bv[j].y, acc[i][j]));
        }
        __syncthreads();
    }

    // h1 = relu(acc + b1)
#pragma unroll
    for (int j = 0; j < 8; j++) {
        float bias = b1[tx + 32 * j];
#pragma unroll
        for (int i = 0; i < 4; i++)
            h1[(ty + 8 * i) * 256 + tx + 32 * j] = fmaxf(acc[i][j] + bias, 0.f);
    }
    __syncthreads();

    // h2 = relu(h1 @ W2 + b2); thread -> (c2 = t&127, rows half*16..+15)
    const int c2 = t & 127, half = t >> 7;
    float h2a[16];
    {
        float bb2 = b2[c2];
#pragma unroll
        for (int i = 0; i < 16; i++) h2a[i] = bb2;
    }
    for (int c4 = 0; c4 < 64; c4++) {
        float w0 = W2[(c4 * 4 + 0) * HID2 + c2];
        float w1v = W2[(c4 * 4 + 1) * HID2 + c2];
        float w2v = W2[(c4 * 4 + 2) * HID2 + c2];
        float w3v = W2[(c4 * 4 + 3) * HID2 + c2];
#pragma unroll
        for (int i = 0; i < 16; i++) {
            float4 h4 = *(const float4*)&h1[(half * 16 + i) * 256 + c4 * 4];
            h2a[i] = fmaf(h4.x, w0, fmaf(h4.y, w1v, fmaf(h4.z, w2v, fmaf(h4.w, w3v, h2a[i]))));
        }
    }
#pragma unroll
    for (int i = 0; i < 16; i++)
        h2b[(half * 16 + i) * 129 + c2] = fmaxf(h2a[i], 0.f);
    __syncthreads();

    // p2 + final sigmoid
    if (t < 32) {
        int bb = bM + t;
        float s = 0.f;
        for (int c = 0; c < HID2; c++) s = fmaf(h2b[t * 129 + c], outW[NSP * EDIM + c], s);
        float logit = logit0[bb] + p1[bb] + s;
        out[bb] = 1.f / (1.f + __expf(-logit));
    }
}

// ---------------------------------------------------------------------------
extern "C" void kernel_launch(void* const* d_in, const int* in_sizes, int n_in,
                              void* d_out, int out_size, void* d_ws, size_t ws_size,
                              hipStream_t stream) {
    const float* X    = (const float*)d_in[0];
    const int*   sidx = (const int*)d_in[1];
    const float* emb  = (const float*)d_in[2];
    const float* Wq   = (const float*)d_in[3];
    const float* Wk   = (const float*)d_in[4];
    const float* Wv   = (const float*)d_in[5];
    const float* Wres = (const float*)d_in[6];
    const float* W1   = (const float*)d_in[7];
    const float* b1   = (const float*)d_in[8];
    const float* W2   = (const float*)d_in[9];
    const float* b2   = (const float*)d_in[10];
    const float* outW = (const float*)d_in[11];
    const float* linW = (const float*)d_in[12];
    const float* linb = (const float*)d_in[13];
    float* out = (float*)d_out;

    float* logit0 = (float*)d_ws;        // B floats
    float* p1     = logit0 + BATCH;      // B floats

    k_lin<<<BATCH / 256, 256, 0, stream>>>(X, linW, linb, logit0);
    k_interact<<<BATCH / 2, 128, 0, stream>>>(sidx, emb, Wq, Wk, Wv, Wres, outW, p1);
    k_dnn<<<BATCH / 32, 256, 0, stream>>>(X, sidx, emb, W1, b1, W2, b2, outW, logit0, p1, out);
}

// Round 2
// 1712.627 us; speedup vs baseline: 2.0806x; 2.0806x over previous
//
#include <hip/hip_runtime.h>
#include <math.h>

#define BATCH 32768
#define NSP 26
#define NDN 13
#define VOC 10000
#define EDIM 64
#define NLAY 3
#define HID1 256
#define HID2 128
#define DIN 1677          // 13 + 26*64
#define XW 39             // NSP + NDN

typedef short short8 __attribute__((ext_vector_type(8)));
typedef short short4v __attribute__((ext_vector_type(4)));
typedef float float4v __attribute__((ext_vector_type(4)));

__device__ __forceinline__ unsigned short f2b(float f) {
    unsigned u = __builtin_bit_cast(unsigned, f);
    u += 0x7FFFu + ((u >> 16) & 1u);          // RNE
    return (unsigned short)(u >> 16);
}
__device__ __forceinline__ float b2f(unsigned short h) {
    unsigned u = ((unsigned)h) << 16;
    return __builtin_bit_cast(float, u);
}

// ---------------------------------------------------------------------------
// K0: pack Wq/Wk/Wv/Wres into MFMA B-fragment order, bf16.
// layout: [l][m][nt(4)][kt(2)][lane(64)][j(8)]  -> lane reads 16B contiguous.
// element = W[l][ kt*32 + (lane>>4)*8 + j ][ nt*16 + (lane&15) ]
// ---------------------------------------------------------------------------
__global__ void k_pack(const float* __restrict__ Wq, const float* __restrict__ Wk,
                       const float* __restrict__ Wv, const float* __restrict__ Wr,
                       unsigned short* __restrict__ pW) {
    int tid = blockIdx.x * 256 + threadIdx.x;   // 49152 total
    int j    = tid & 7;
    int lane = (tid >> 3) & 63;
    int kt   = (tid >> 9) & 1;
    int nt   = (tid >> 10) & 3;
    int m    = (tid >> 12) & 3;
    int l    = tid >> 14;
    const float* W = (m == 0) ? Wq : (m == 1) ? Wk : (m == 2) ? Wv : Wr;
    int k = kt * 32 + (lane >> 4) * 8 + j;
    int n = nt * 16 + (lane & 15);
    pW[tid] = f2b(W[l * EDIM * EDIM + k * EDIM + n]);
}

// ---------------------------------------------------------------------------
// K1: logit0[b] = relu(X[b,:] @ lin_W + lin_b)
// ---------------------------------------------------------------------------
__global__ void k_lin(const float* __restrict__ X, const float* __restrict__ lw,
                      const float* __restrict__ lb, float* __restrict__ logit0) {
    int b = blockIdx.x * 256 + threadIdx.x;
    float s = lb[0];
    const float* xr = X + (long)b * XW;
#pragma unroll
    for (int i = 0; i < XW; i++) s = fmaf(xr[i], lw[i], s);
    logit0[b] = fmaxf(s, 0.f);
}

// ---------------------------------------------------------------------------
// K2: fused 3-layer AutoInt interaction, MFMA bf16. One wave = one sample.
// M=26 padded to 32 (2 M-tiles of 16). LDS per wave 18944B -> 8 waves/CU.
//   att: [32][72] bf16 row-major        (A-frag reads: ds_read_b128, 2-way ok)
//   qb : [32][72]  Q row-major          (aliased by P = [2][32][40] afterwards)
//   kb : [32][72]  K row-major
//   vtb: [64][40]  V^T (dcol x key)     (B-frag reads contiguous)
// R stays in C-layout registers; epilogue fuses relu(O + R) -> att.
// ---------------------------------------------------------------------------
__global__ __launch_bounds__(64) void k_interact(
    const int* __restrict__ sidx, const float* __restrict__ emb,
    const unsigned short* __restrict__ pW, const float* __restrict__ outW,
    float* __restrict__ p1)
{
    __shared__ __align__(16) unsigned short smem[32*72*3 + 64*40];
    unsigned short* att = smem;
    unsigned short* qb  = smem + 32*72;
    unsigned short* kb  = smem + 32*72*2;
    unsigned short* vtb = smem + 32*72*3;
    unsigned short* P   = qb;               // [2][32][40], spans qb+kb

    const int lane = threadIdx.x;
    const int b    = blockIdx.x;
    const int quad = lane >> 4;
    const int c16  = lane & 15;
    const float4v zero4 = {0.f, 0.f, 0.f, 0.f};

    // gather embeddings -> att (bf16), coalesced over lane=e
#pragma unroll
    for (int f = 0; f < NSP; f++) {
        int idx = sidx[b * NSP + f];
        att[f * 72 + lane] = f2b(emb[((long)(f * VOC + idx)) * EDIM + lane]);
    }
#pragma unroll
    for (int r = NSP; r < 32; r++) att[r * 72 + lane] = 0;   // zero pad rows
    __syncthreads();

    for (int l = 0; l < NLAY; l++) {
        // ---- A-fragments of att (shared by all 4 projections) ----
        short8 Aatt[2][2];
#pragma unroll
        for (int mt = 0; mt < 2; mt++)
#pragma unroll
            for (int kt = 0; kt < 2; kt++)
                Aatt[mt][kt] = *(const short8*)&att[(mt*16 + c16)*72 + kt*32 + quad*8];

        const unsigned short* wl = pW + l * 16384;
        float4v Rf[2][4];

        // ---- projections: m = 0:Q 1:K 2:V 3:R ----
#pragma unroll
        for (int m = 0; m < 4; m++) {
            short8 Bf[4][2];
#pragma unroll
            for (int nt = 0; nt < 4; nt++)
#pragma unroll
                for (int kt = 0; kt < 2; kt++)
                    Bf[nt][kt] = *(const short8*)&wl[(m*8 + nt*2 + kt)*512 + lane*8];
            float4v C[2][4];
#pragma unroll
            for (int mt = 0; mt < 2; mt++)
#pragma unroll
                for (int nt = 0; nt < 4; nt++) {
                    float4v acc = __builtin_amdgcn_mfma_f32_16x16x32_bf16(
                        Aatt[mt][0], Bf[nt][0], zero4, 0, 0, 0);
                    C[mt][nt] = __builtin_amdgcn_mfma_f32_16x16x32_bf16(
                        Aatt[mt][1], Bf[nt][1], acc, 0, 0, 0);
                }
            if (m == 0 || m == 1) {
                unsigned short* dst = (m == 0) ? qb : kb;
#pragma unroll
                for (int mt = 0; mt < 2; mt++)
#pragma unroll
                    for (int nt = 0; nt < 4; nt++)
#pragma unroll
                        for (int reg = 0; reg < 4; reg++)
                            dst[(mt*16 + quad*4 + reg)*72 + nt*16 + c16] = f2b(C[mt][nt][reg]);
            } else if (m == 2) {
                // V^T: [dcol][key]; lane's 4 regs are 4 consecutive keys -> b64 write
#pragma unroll
                for (int mt = 0; mt < 2; mt++)
#pragma unroll
                    for (int nt = 0; nt < 4; nt++) {
                        short4v v;
                        v[0] = (short)f2b(C[mt][nt][0]);
                        v[1] = (short)f2b(C[mt][nt][1]);
                        v[2] = (short)f2b(C[mt][nt][2]);
                        v[3] = (short)f2b(C[mt][nt][3]);
                        *(short4v*)&vtb[(nt*16 + c16)*40 + mt*16 + quad*4] = v;
                    }
            } else {
#pragma unroll
                for (int mt = 0; mt < 2; mt++)
#pragma unroll
                    for (int nt = 0; nt < 4; nt++) Rf[mt][nt] = C[mt][nt];
            }
        }
        __syncthreads();

        // ---- QK^T: S[h][q][key], K=dhead=32 (1 K-tile) ----
        short8 Qf[2][2], Kf[2][2];
#pragma unroll
        for (int mt = 0; mt < 2; mt++)
#pragma unroll
            for (int h = 0; h < 2; h++)
                Qf[mt][h] = *(const short8*)&qb[(mt*16 + c16)*72 + h*32 + quad*8];
#pragma unroll
        for (int nt = 0; nt < 2; nt++)
#pragma unroll
            for (int h = 0; h < 2; h++)
                Kf[nt][h] = *(const short8*)&kb[(nt*16 + c16)*72 + h*32 + quad*8];
        float4v S[2][2][2];
#pragma unroll
        for (int h = 0; h < 2; h++)
#pragma unroll
            for (int mt = 0; mt < 2; mt++)
#pragma unroll
                for (int nt = 0; nt < 2; nt++)
                    S[h][mt][nt] = __builtin_amdgcn_mfma_f32_16x16x32_bf16(
                        Qf[mt][h], Kf[nt][h], zero4, 0, 0, 0);
        __syncthreads();

        // ---- S -> P buffer (bf16, [h][32][40]) ----
#pragma unroll
        for (int h = 0; h < 2; h++)
#pragma unroll
            for (int mt = 0; mt < 2; mt++)
#pragma unroll
                for (int nt = 0; nt < 2; nt++)
#pragma unroll
                    for (int reg = 0; reg < 4; reg++)
                        P[h*1280 + (mt*16 + quad*4 + reg)*40 + nt*16 + c16] =
                            f2b(S[h][mt][nt][reg]);
        __syncthreads();

        // ---- row softmax: lane -> (h, q), 52 active lanes ----
        if (lane < 2 * NSP) {
            int h = lane / NSP, q = lane % NSP;
            unsigned short* row = &P[h*1280 + q*40];
            short8 r0 = *(const short8*)&row[0];
            short8 r1 = *(const short8*)&row[8];
            short8 r2 = *(const short8*)&row[16];
            short8 r3 = *(const short8*)&row[24];
            float v[26];
#pragma unroll
            for (int j = 0; j < 8; j++)  v[j]      = b2f((unsigned short)r0[j]);
#pragma unroll
            for (int j = 0; j < 8; j++)  v[8 + j]  = b2f((unsigned short)r1[j]);
#pragma unroll
            for (int j = 0; j < 8; j++)  v[16 + j] = b2f((unsigned short)r2[j]);
            v[24] = b2f((unsigned short)r3[0]);
            v[25] = b2f((unsigned short)r3[1]);
            float mx = v[0];
#pragma unroll
            for (int j = 1; j < 26; j++) mx = fmaxf(mx, v[j]);
            float sum = 0.f;
#pragma unroll
            for (int j = 0; j < 26; j++) { v[j] = __expf(v[j] - mx); sum += v[j]; }
            float inv = 1.f / sum;
            short8 w0, w1, w2, w3;
#pragma unroll
            for (int j = 0; j < 8; j++)  w0[j] = (short)f2b(v[j] * inv);
#pragma unroll
            for (int j = 0; j < 8; j++)  w1[j] = (short)f2b(v[8 + j] * inv);
#pragma unroll
            for (int j = 0; j < 8; j++)  w2[j] = (short)f2b(v[16 + j] * inv);
            w3[0] = (short)f2b(v[24] * inv);
            w3[1] = (short)f2b(v[25] * inv);
#pragma unroll
            for (int j = 2; j < 8; j++)  w3[j] = 0;     // pad keys 26..31 -> 0
            *(short8*)&row[0]  = w0;
            *(short8*)&row[8]  = w1;
            *(short8*)&row[16] = w2;
            *(short8*)&row[24] = w3;
        }
        __syncthreads();

        // ---- P @ V: O[h][q][d], K=key=32 (1 K-tile) ----
        short8 Pf[2][2], Vf[2][2];
#pragma unroll
        for (int h = 0; h < 2; h++)
#pragma unroll
            for (int mt = 0; mt < 2; mt++)
                Pf[h][mt] = *(const short8*)&P[h*1280 + (mt*16 + c16)*40 + quad*8];
#pragma unroll
        for (int h = 0; h < 2; h++)
#pragma unroll
            for (int nt2 = 0; nt2 < 2; nt2++)
                Vf[h][nt2] = *(const short8*)&vtb[(h*32 + nt2*16 + c16)*40 + quad*8];
        float4v Of[2][4];
#pragma unroll
        for (int h = 0; h < 2; h++)
#pragma unroll
            for (int mt = 0; mt < 2; mt++)
#pragma unroll
                for (int nt2 = 0; nt2 < 2; nt2++)
                    Of[mt][h*2 + nt2] = __builtin_amdgcn_mfma_f32_16x16x32_bf16(
                        Pf[h][mt], Vf[h][nt2], zero4, 0, 0, 0);
        __syncthreads();

        // ---- epilogue: att = relu(O + R) ----
#pragma unroll
        for (int mt = 0; mt < 2; mt++)
#pragma unroll
            for (int nt = 0; nt < 4; nt++)
#pragma unroll
                for (int reg = 0; reg < 4; reg++) {
                    float val = Of[mt][nt][reg] + Rf[mt][nt][reg];
                    att[(mt*16 + quad*4 + reg)*72 + nt*16 + c16] = f2b(fmaxf(val, 0.f));
                }
        __syncthreads();
    }

    // ---- p1[b] = att_flat @ out_W[0:1664] ----
    float s = 0.f;
#pragma unroll
    for (int f = 0; f < NSP; f++)
        s = fmaf(b2f(att[f*72 + lane]), outW[f*EDIM + lane], s);
#pragma unroll
    for (int off = 32; off > 0; off >>= 1) s += __shfl_down(s, off);
    if (lane == 0) p1[b] = s;
}

// ---------------------------------------------------------------------------
// K3: fused DNN + final (unchanged from round 1).
// ---------------------------------------------------------------------------
__global__ __launch_bounds__(256) void k_dnn(
    const float* __restrict__ X, const int* __restrict__ sidx,
    const float* __restrict__ emb, const float* __restrict__ W1,
    const float* __restrict__ b1, const float* __restrict__ W2,
    const float* __restrict__ b2, const float* __restrict__ outW,
    const float* __restrict__ logit0, const float* __restrict__ p1,
    float* __restrict__ out)
{
    __shared__ float smem[640 + 4608 + 8192];       // 53760 B
    float* A   = smem;                  // [32][20]
    float* BT  = smem + 640;            // [256][18]
    float* h1  = smem + 640 + 4608;     // [32][256]
    float* h2b = smem;                  // alias after GEMM1: [32][129]

    const int t  = threadIdx.x;
    const int bM = blockIdx.x * 32;
    const int tx = t & 31, ty = t >> 5;

    float acc[4][8];
#pragma unroll
    for (int i = 0; i < 4; i++)
#pragma unroll
        for (int j = 0; j < 8; j++) acc[i][j] = 0.f;

    for (int ch = 0; ch < (DIN + 15) / 16; ch++) {
        const int k0 = ch * 16;
        for (int e = t; e < 512; e += 256) {
            int kk = e & 15, r = e >> 4;
            int k = k0 + kk;
            float v = 0.f;
            if (k < DIN) {
                int bb = bM + r;
                if (k < NDN) v = X[(long)bb * XW + NSP + k];
                else {
                    int km = k - NDN;
                    int f = km >> 6, ee = km & 63;
                    v = emb[((long)f * VOC + sidx[bb * NSP + f]) * EDIM + ee];
                }
            }
            A[r * 20 + kk] = v;
        }
        for (int e = t; e < 4096; e += 256) {
            int c = e & 255, kk = e >> 8;
            int k = k0 + kk;
            BT[c * 18 + kk] = (k < DIN) ? W1[(long)k * HID1 + c] : 0.f;
        }
        __syncthreads();
#pragma unroll
        for (int kk2 = 0; kk2 < 8; kk2++) {
            float2 bv[8], av[4];
#pragma unroll
            for (int j = 0; j < 8; j++) bv[j] = *(const float2*)&BT[(tx + 32 * j) * 18 + kk2 * 2];
#pragma unroll
            for (int i = 0; i < 4; i++) av[i] = *(const float2*)&A[(ty + 8 * i) * 20 + kk2 * 2];
#pragma unroll
            for (int i = 0; i < 4; i++)
#pragma unroll
                for (int j = 0; j < 8; j++)
                    acc[i][j] = fmaf(av[i].x, bv[j].x, fmaf(av[i].y, bv[j].y, acc[i][j]));
        }
        __syncthreads();
    }

#pragma unroll
    for (int j = 0; j < 8; j++) {
        float bias = b1[tx + 32 * j];
#pragma unroll
        for (int i = 0; i < 4; i++)
            h1[(ty + 8 * i) * 256 + tx + 32 * j] = fmaxf(acc[i][j] + bias, 0.f);
    }
    __syncthreads();

    const int c2 = t & 127, half = t >> 7;
    float h2a[16];
    {
        float bb2 = b2[c2];
#pragma unroll
        for (int i = 0; i < 16; i++) h2a[i] = bb2;
    }
    for (int c4 = 0; c4 < 64; c4++) {
        float w0 = W2[(c4 * 4 + 0) * HID2 + c2];
        float w1v = W2[(c4 * 4 + 1) * HID2 + c2];
        float w2v = W2[(c4 * 4 + 2) * HID2 + c2];
        float w3v = W2[(c4 * 4 + 3) * HID2 + c2];
#pragma unroll
        for (int i = 0; i < 16; i++) {
            float4 h4 = *(const float4*)&h1[(half * 16 + i) * 256 + c4 * 4];
            h2a[i] = fmaf(h4.x, w0, fmaf(h4.y, w1v, fmaf(h4.z, w2v, fmaf(h4.w, w3v, h2a[i]))));
        }
    }
#pragma unroll
    for (int i = 0; i < 16; i++)
        h2b[(half * 16 + i) * 129 + c2] = fmaxf(h2a[i], 0.f);
    __syncthreads();

    if (t < 32) {
        int bb = bM + t;
        float s = 0.f;
        for (int c = 0; c < HID2; c++) s = fmaf(h2b[t * 129 + c], outW[NSP * EDIM + c], s);
        float logit = logit0[bb] + p1[bb] + s;
        out[bb] = 1.f / (1.f + __expf(-logit));
    }
}

// ---------------------------------------------------------------------------
extern "C" void kernel_launch(void* const* d_in, const int* in_sizes, int n_in,
                              void* d_out, int out_size, void* d_ws, size_t ws_size,
                              hipStream_t stream) {
    const float* X    = (const float*)d_in[0];
    const int*   sidx = (const int*)d_in[1];
    const float* emb  = (const float*)d_in[2];
    const float* Wq   = (const float*)d_in[3];
    const float* Wk   = (const float*)d_in[4];
    const float* Wv   = (const float*)d_in[5];
    const float* Wres = (const float*)d_in[6];
    const float* W1   = (const float*)d_in[7];
    const float* b1   = (const float*)d_in[8];
    const float* W2   = (const float*)d_in[9];
    const float* b2   = (const float*)d_in[10];
    const float* outW = (const float*)d_in[11];
    const float* linW = (const float*)d_in[12];
    const float* linb = (const float*)d_in[13];
    float* out = (float*)d_out;

    float* logit0 = (float*)d_ws;                        // B floats
    float* p1     = logit0 + BATCH;                      // B floats
    unsigned short* pW = (unsigned short*)(p1 + BATCH);  // 49152 bf16

    k_lin<<<BATCH / 256, 256, 0, stream>>>(X, linW, linb, logit0);
    k_pack<<<192, 256, 0, stream>>>(Wq, Wk, Wv, Wres, pW);
    k_interact<<<BATCH, 64, 0, stream>>>(sidx, emb, pW, outW, p1);
    k_dnn<<<BATCH / 32, 256, 0, stream>>>(X, sidx, emb, W1, b1, W2, b2, outW, logit0, p1, out);
}

// Round 3
// 632.247 us; speedup vs baseline: 5.6360x; 2.7088x over previous
//
#include <hip/hip_runtime.h>
#include <math.h>

#define BATCH 32768
#define NSP 26
#define NDN 13
#define VOC 10000
#define EDIM 64
#define NLAY 3
#define HID1 256
#define HID2 128
#define DIN 1677          // 13 + 26*64
#define XW 39             // NSP + NDN
#define KC1 53            // GEMM1 K-chunks of 32 (K padded 1677 -> 1696)

typedef short short8 __attribute__((ext_vector_type(8)));
typedef short short4v __attribute__((ext_vector_type(4)));
typedef float float4v __attribute__((ext_vector_type(4)));

__device__ __forceinline__ unsigned short f2b(float f) {
    unsigned u = __builtin_bit_cast(unsigned, f);
    u += 0x7FFFu + ((u >> 16) & 1u);          // RNE
    return (unsigned short)(u >> 16);
}
__device__ __forceinline__ float b2f(unsigned short h) {
    unsigned u = ((unsigned)h) << 16;
    return __builtin_bit_cast(float, u);
}

// ---------------------------------------------------------------------------
// K0: pack all weights into MFMA B-fragment order (bf16).
//  bid <  192 : Wq/Wk/Wv/Wres -> pW  [l][m][nt4][kt2][lane][j8]
//  192..1887  : W1            -> pW1 [kc53][nt16][lane][j8]   (k>=1677 -> 0)
//  1888..2015 : W2            -> pW2 [kc8][nt8][lane][j8]
// fragment element = W[k = kc*32 + (lane>>4)*8 + j][n = nt*16 + (lane&15)]
// ---------------------------------------------------------------------------
__global__ void k_pack(const float* __restrict__ Wq, const float* __restrict__ Wk,
                       const float* __restrict__ Wv, const float* __restrict__ Wr,
                       const float* __restrict__ W1, const float* __restrict__ W2,
                       unsigned short* __restrict__ pW,
                       unsigned short* __restrict__ pW1,
                       unsigned short* __restrict__ pW2) {
    int bid = blockIdx.x;
    if (bid < 192) {
        int tid = bid * 256 + threadIdx.x;   // 49152 total
        int j    = tid & 7;
        int lane = (tid >> 3) & 63;
        int kt   = (tid >> 9) & 1;
        int nt   = (tid >> 10) & 3;
        int m    = (tid >> 12) & 3;
        int l    = tid >> 14;
        const float* W = (m == 0) ? Wq : (m == 1) ? Wk : (m == 2) ? Wv : Wr;
        int k = kt * 32 + ((lane >> 4) << 3) + j;
        int n = nt * 16 + (lane & 15);
        pW[tid] = f2b(W[l * EDIM * EDIM + k * EDIM + n]);
    } else if (bid < 1888) {
        int tid = (bid - 192) * 256 + threadIdx.x;   // 434176 total
        int j    = tid & 7;
        int lane = (tid >> 3) & 63;
        int nt   = (tid >> 9) & 15;
        int kc   = tid >> 13;
        int k = kc * 32 + ((lane >> 4) << 3) + j;
        int n = nt * 16 + (lane & 15);
        pW1[tid] = (k < DIN) ? f2b(W1[(long)k * HID1 + n]) : (unsigned short)0;
    } else {
        int tid = (bid - 1888) * 256 + threadIdx.x;  // 32768 total
        int j    = tid & 7;
        int lane = (tid >> 3) & 63;
        int nt   = (tid >> 9) & 7;
        int kc   = tid >> 12;
        int k = kc * 32 + ((lane >> 4) << 3) + j;
        int n = nt * 16 + (lane & 15);
        pW2[tid] = f2b(W2[(long)k * HID2 + n]);
    }
}

// ---------------------------------------------------------------------------
// K1: logit0[b] = relu(X[b,:] @ lin_W + lin_b)
// ---------------------------------------------------------------------------
__global__ void k_lin(const float* __restrict__ X, const float* __restrict__ lw,
                      const float* __restrict__ lb, float* __restrict__ logit0) {
    int b = blockIdx.x * 256 + threadIdx.x;
    float s = lb[0];
    const float* xr = X + (long)b * XW;
#pragma unroll
    for (int i = 0; i < XW; i++) s = fmaf(xr[i], lw[i], s);
    logit0[b] = fmaxf(s, 0.f);
}

// ---------------------------------------------------------------------------
// K2: fused 3-layer AutoInt interaction, MFMA bf16 (unchanged from round 2).
// ---------------------------------------------------------------------------
__global__ __launch_bounds__(64) void k_interact(
    const int* __restrict__ sidx, const float* __restrict__ emb,
    const unsigned short* __restrict__ pW, const float* __restrict__ outW,
    float* __restrict__ p1)
{
    __shared__ __align__(16) unsigned short smem[32*72*3 + 64*40];
    unsigned short* att = smem;
    unsigned short* qb  = smem + 32*72;
    unsigned short* kb  = smem + 32*72*2;
    unsigned short* vtb = smem + 32*72*3;
    unsigned short* P   = qb;               // [2][32][40], spans qb+kb

    const int lane = threadIdx.x;
    const int b    = blockIdx.x;
    const int quad = lane >> 4;
    const int c16  = lane & 15;
    const float4v zero4 = {0.f, 0.f, 0.f, 0.f};

#pragma unroll
    for (int f = 0; f < NSP; f++) {
        int idx = sidx[b * NSP + f];
        att[f * 72 + lane] = f2b(emb[((long)(f * VOC + idx)) * EDIM + lane]);
    }
#pragma unroll
    for (int r = NSP; r < 32; r++) att[r * 72 + lane] = 0;
    __syncthreads();

    for (int l = 0; l < NLAY; l++) {
        short8 Aatt[2][2];
#pragma unroll
        for (int mt = 0; mt < 2; mt++)
#pragma unroll
            for (int kt = 0; kt < 2; kt++)
                Aatt[mt][kt] = *(const short8*)&att[(mt*16 + c16)*72 + kt*32 + quad*8];

        const unsigned short* wl = pW + l * 16384;
        float4v Rf[2][4];

#pragma unroll
        for (int m = 0; m < 4; m++) {
            short8 Bf[4][2];
#pragma unroll
            for (int nt = 0; nt < 4; nt++)
#pragma unroll
                for (int kt = 0; kt < 2; kt++)
                    Bf[nt][kt] = *(const short8*)&wl[(m*8 + nt*2 + kt)*512 + lane*8];
            float4v C[2][4];
#pragma unroll
            for (int mt = 0; mt < 2; mt++)
#pragma unroll
                for (int nt = 0; nt < 4; nt++) {
                    float4v acc = __builtin_amdgcn_mfma_f32_16x16x32_bf16(
                        Aatt[mt][0], Bf[nt][0], zero4, 0, 0, 0);
                    C[mt][nt] = __builtin_amdgcn_mfma_f32_16x16x32_bf16(
                        Aatt[mt][1], Bf[nt][1], acc, 0, 0, 0);
                }
            if (m == 0 || m == 1) {
                unsigned short* dst = (m == 0) ? qb : kb;
#pragma unroll
                for (int mt = 0; mt < 2; mt++)
#pragma unroll
                    for (int nt = 0; nt < 4; nt++)
#pragma unroll
                        for (int reg = 0; reg < 4; reg++)
                            dst[(mt*16 + quad*4 + reg)*72 + nt*16 + c16] = f2b(C[mt][nt][reg]);
            } else if (m == 2) {
#pragma unroll
                for (int mt = 0; mt < 2; mt++)
#pragma unroll
                    for (int nt = 0; nt < 4; nt++) {
                        short4v v;
                        v[0] = (short)f2b(C[mt][nt][0]);
                        v[1] = (short)f2b(C[mt][nt][1]);
                        v[2] = (short)f2b(C[mt][nt][2]);
                        v[3] = (short)f2b(C[mt][nt][3]);
                        *(short4v*)&vtb[(nt*16 + c16)*40 + mt*16 + quad*4] = v;
                    }
            } else {
#pragma unroll
                for (int mt = 0; mt < 2; mt++)
#pragma unroll
                    for (int nt = 0; nt < 4; nt++) Rf[mt][nt] = C[mt][nt];
            }
        }
        __syncthreads();

        short8 Qf[2][2], Kf[2][2];
#pragma unroll
        for (int mt = 0; mt < 2; mt++)
#pragma unroll
            for (int h = 0; h < 2; h++)
                Qf[mt][h] = *(const short8*)&qb[(mt*16 + c16)*72 + h*32 + quad*8];
#pragma unroll
        for (int nt = 0; nt < 2; nt++)
#pragma unroll
            for (int h = 0; h < 2; h++)
                Kf[nt][h] = *(const short8*)&kb[(nt*16 + c16)*72 + h*32 + quad*8];
        float4v S[2][2][2];
#pragma unroll
        for (int h = 0; h < 2; h++)
#pragma unroll
            for (int mt = 0; mt < 2; mt++)
#pragma unroll
                for (int nt = 0; nt < 2; nt++)
                    S[h][mt][nt] = __builtin_amdgcn_mfma_f32_16x16x32_bf16(
                        Qf[mt][h], Kf[nt][h], zero4, 0, 0, 0);
        __syncthreads();

#pragma unroll
        for (int h = 0; h < 2; h++)
#pragma unroll
            for (int mt = 0; mt < 2; mt++)
#pragma unroll
                for (int nt = 0; nt < 2; nt++)
#pragma unroll
                    for (int reg = 0; reg < 4; reg++)
                        P[h*1280 + (mt*16 + quad*4 + reg)*40 + nt*16 + c16] =
                            f2b(S[h][mt][nt][reg]);
        __syncthreads();

        if (lane < 2 * NSP) {
            int h = lane / NSP, q = lane % NSP;
            unsigned short* row = &P[h*1280 + q*40];
            short8 r0 = *(const short8*)&row[0];
            short8 r1 = *(const short8*)&row[8];
            short8 r2 = *(const short8*)&row[16];
            short8 r3 = *(const short8*)&row[24];
            float v[26];
#pragma unroll
            for (int j = 0; j < 8; j++)  v[j]      = b2f((unsigned short)r0[j]);
#pragma unroll
            for (int j = 0; j < 8; j++)  v[8 + j]  = b2f((unsigned short)r1[j]);
#pragma unroll
            for (int j = 0; j < 8; j++)  v[16 + j] = b2f((unsigned short)r2[j]);
            v[24] = b2f((unsigned short)r3[0]);
            v[25] = b2f((unsigned short)r3[1]);
            float mx = v[0];
#pragma unroll
            for (int j = 1; j < 26; j++) mx = fmaxf(mx, v[j]);
            float sum = 0.f;
#pragma unroll
            for (int j = 0; j < 26; j++) { v[j] = __expf(v[j] - mx); sum += v[j]; }
            float inv = 1.f / sum;
            short8 w0, w1, w2, w3;
#pragma unroll
            for (int j = 0; j < 8; j++)  w0[j] = (short)f2b(v[j] * inv);
#pragma unroll
            for (int j = 0; j < 8; j++)  w1[j] = (short)f2b(v[8 + j] * inv);
#pragma unroll
            for (int j = 0; j < 8; j++)  w2[j] = (short)f2b(v[16 + j] * inv);
            w3[0] = (short)f2b(v[24] * inv);
            w3[1] = (short)f2b(v[25] * inv);
#pragma unroll
            for (int j = 2; j < 8; j++)  w3[j] = 0;
            *(short8*)&row[0]  = w0;
            *(short8*)&row[8]  = w1;
            *(short8*)&row[16] = w2;
            *(short8*)&row[24] = w3;
        }
        __syncthreads();

        short8 Pf[2][2], Vf[2][2];
#pragma unroll
        for (int h = 0; h < 2; h++)
#pragma unroll
            for (int mt = 0; mt < 2; mt++)
                Pf[h][mt] = *(const short8*)&P[h*1280 + (mt*16 + c16)*40 + quad*8];
#pragma unroll
        for (int h = 0; h < 2; h++)
#pragma unroll
            for (int nt2 = 0; nt2 < 2; nt2++)
                Vf[h][nt2] = *(const short8*)&vtb[(h*32 + nt2*16 + c16)*40 + quad*8];
        float4v Of[2][4];
#pragma unroll
        for (int h = 0; h < 2; h++)
#pragma unroll
            for (int mt = 0; mt < 2; mt++)
#pragma unroll
                for (int nt2 = 0; nt2 < 2; nt2++)
                    Of[mt][h*2 + nt2] = __builtin_amdgcn_mfma_f32_16x16x32_bf16(
                        Pf[h][mt], Vf[h][nt2], zero4, 0, 0, 0);
        __syncthreads();

#pragma unroll
        for (int mt = 0; mt < 2; mt++)
#pragma unroll
            for (int nt = 0; nt < 4; nt++)
#pragma unroll
                for (int reg = 0; reg < 4; reg++) {
                    float val = Of[mt][nt][reg] + Rf[mt][nt][reg];
                    att[(mt*16 + quad*4 + reg)*72 + nt*16 + c16] = f2b(fmaxf(val, 0.f));
                }
        __syncthreads();
    }

    float s = 0.f;
#pragma unroll
    for (int f = 0; f < NSP; f++)
        s = fmaf(b2f(att[f*72 + lane]), outW[f*EDIM + lane], s);
#pragma unroll
    for (int off = 32; off > 0; off >>= 1) s += __shfl_down(s, off);
    if (lane == 0) p1[b] = s;
}

// ---------------------------------------------------------------------------
// K3: fused DNN, MFMA bf16. Block = 256 threads = 4 waves, M-tile = 64 samples.
// GEMM1: 64x1696 @ 1696x256. Wave w owns h1 columns [w*64, w*64+64).
//   per K-chunk(32): stage A 64x32 bf16 -> LDS (stride 40), B-frags straight
//   from pre-packed pW1 (global, L2-hot), 16 MFMA.
// h1 (bf16, LDS, stride 264) -> GEMM2 64x256 @ 256x128 (wave w: cols w*32..)
// -> h2 (LDS) -> p2 dot + sigmoid epilogue.
// ---------------------------------------------------------------------------
__global__ __launch_bounds__(256) void k_dnn(
    const float* __restrict__ X, const int* __restrict__ sidx,
    const float* __restrict__ emb, const unsigned short* __restrict__ pW1,
    const float* __restrict__ b1, const unsigned short* __restrict__ pW2,
    const float* __restrict__ b2, const float* __restrict__ outW,
    const float* __restrict__ logit0, const float* __restrict__ p1,
    float* __restrict__ out)
{
    __shared__ __align__(16) unsigned short smem[2560 + 16896 + 8704];  // 56320 B
    unsigned short* Abuf  = smem;                 // [64][40]
    unsigned short* h1buf = smem + 2560;          // [64][264]
    unsigned short* h2buf = smem + 2560 + 16896;  // [64][136]

    const int t    = threadIdx.x;
    const int lane = t & 63;
    const int w    = t >> 6;
    const int quad = lane >> 4;
    const int c16  = lane & 15;
    const int bM   = blockIdx.x * 64;

    float4v acc[4][4];
#pragma unroll
    for (int mt = 0; mt < 4; mt++)
#pragma unroll
        for (int nt = 0; nt < 4; nt++) acc[mt][nt] = (float4v){0.f, 0.f, 0.f, 0.f};

    const int kk = t & 31;   // k within chunk
    const int sr = t >> 5;   // sample base (0..7)

    for (int kc = 0; kc < KC1; kc++) {
        // ---- stage A chunk: 64 samples x 32 k (bf16) ----
        const int k   = kc * 32 + kk;
        const bool ok = k < DIN;
        const bool isd = k < NDN;
        const int km = k - NDN;
        const int f = km >> 6, e = km & 63;
#pragma unroll
        for (int r = 0; r < 8; r++) {
            int s = sr + r * 8;
            float v = 0.f;
            if (ok)
                v = isd ? X[(long)(bM + s) * XW + NSP + k]
                        : emb[((long)(f * VOC + sidx[(bM + s) * NSP + f])) * EDIM + e];
            Abuf[s * 40 + kk] = f2b(v);
        }
        __syncthreads();

        short8 Bf[4], Af[4];
#pragma unroll
        for (int nt = 0; nt < 4; nt++)
            Bf[nt] = *(const short8*)&pW1[((long)(kc * 16 + w * 4 + nt) * 64 + lane) * 8];
#pragma unroll
        for (int mt = 0; mt < 4; mt++)
            Af[mt] = *(const short8*)&Abuf[(mt * 16 + c16) * 40 + quad * 8];
#pragma unroll
        for (int mt = 0; mt < 4; mt++)
#pragma unroll
            for (int nt = 0; nt < 4; nt++)
                acc[mt][nt] = __builtin_amdgcn_mfma_f32_16x16x32_bf16(
                    Af[mt], Bf[nt], acc[mt][nt], 0, 0, 0);
        __syncthreads();
    }

    // ---- h1 = relu(acc + b1) -> LDS bf16 ----
#pragma unroll
    for (int nt = 0; nt < 4; nt++) {
        int n = w * 64 + nt * 16 + c16;
        float bias = b1[n];
#pragma unroll
        for (int mt = 0; mt < 4; mt++)
#pragma unroll
            for (int reg = 0; reg < 4; reg++)
                h1buf[(mt * 16 + quad * 4 + reg) * 264 + n] =
                    f2b(fmaxf(acc[mt][nt][reg] + bias, 0.f));
    }
    __syncthreads();

    // ---- GEMM2: h2 = relu(h1 @ W2 + b2), wave w -> cols [w*32, w*32+32) ----
    float4v acc2[4][2];
#pragma unroll
    for (int mt = 0; mt < 4; mt++)
#pragma unroll
        for (int n2 = 0; n2 < 2; n2++) acc2[mt][n2] = (float4v){0.f, 0.f, 0.f, 0.f};
#pragma unroll
    for (int kc2 = 0; kc2 < 8; kc2++) {
        short8 Bf2[2], Af2[4];
#pragma unroll
        for (int n2 = 0; n2 < 2; n2++)
            Bf2[n2] = *(const short8*)&pW2[((kc2 * 8 + w * 2 + n2) * 64 + lane) * 8];
#pragma unroll
        for (int mt = 0; mt < 4; mt++)
            Af2[mt] = *(const short8*)&h1buf[(mt * 16 + c16) * 264 + kc2 * 32 + quad * 8];
#pragma unroll
        for (int mt = 0; mt < 4; mt++)
#pragma unroll
            for (int n2 = 0; n2 < 2; n2++)
                acc2[mt][n2] = __builtin_amdgcn_mfma_f32_16x16x32_bf16(
                    Af2[mt], Bf2[n2], acc2[mt][n2], 0, 0, 0);
    }
#pragma unroll
    for (int n2 = 0; n2 < 2; n2++) {
        int n = w * 32 + n2 * 16 + c16;
        float bias = b2[n];
#pragma unroll
        for (int mt = 0; mt < 4; mt++)
#pragma unroll
            for (int reg = 0; reg < 4; reg++)
                h2buf[(mt * 16 + quad * 4 + reg) * 136 + n] =
                    f2b(fmaxf(acc2[mt][n2][reg] + bias, 0.f));
    }
    __syncthreads();

    // ---- p2 + final sigmoid ----
    if (t < 64) {
        const float* ow2 = outW + NSP * EDIM;
        float s = 0.f;
#pragma unroll
        for (int c8 = 0; c8 < 16; c8++) {
            short8 h = *(const short8*)&h2buf[t * 136 + c8 * 8];
#pragma unroll
            for (int j = 0; j < 8; j++)
                s = fmaf(b2f((unsigned short)h[j]), ow2[c8 * 8 + j], s);
        }
        int bb = bM + t;
        float logit = logit0[bb] + p1[bb] + s;
        out[bb] = 1.f / (1.f + __expf(-logit));
    }
}

// ---------------------------------------------------------------------------
extern "C" void kernel_launch(void* const* d_in, const int* in_sizes, int n_in,
                              void* d_out, int out_size, void* d_ws, size_t ws_size,
                              hipStream_t stream) {
    const float* X    = (const float*)d_in[0];
    const int*   sidx = (const int*)d_in[1];
    const float* emb  = (const float*)d_in[2];
    const float* Wq   = (const float*)d_in[3];
    const float* Wk   = (const float*)d_in[4];
    const float* Wv   = (const float*)d_in[5];
    const float* Wres = (const float*)d_in[6];
    const float* W1   = (const float*)d_in[7];
    const float* b1   = (const float*)d_in[8];
    const float* W2   = (const float*)d_in[9];
    const float* b2   = (const float*)d_in[10];
    const float* outW = (const float*)d_in[11];
    const float* linW = (const float*)d_in[12];
    const float* linb = (const float*)d_in[13];
    float* out = (float*)d_out;

    float* logit0 = (float*)d_ws;                          // 32768 f
    float* p1     = logit0 + BATCH;                        // 32768 f
    unsigned short* pW  = (unsigned short*)(p1 + BATCH);   // 49152 bf16
    unsigned short* pW1 = pW + 49152;                      // 434176 bf16
    unsigned short* pW2 = pW1 + 434176;                    // 32768 bf16

    k_pack<<<2016, 256, 0, stream>>>(Wq, Wk, Wv, Wres, W1, W2, pW, pW1, pW2);
    k_lin<<<BATCH / 256, 256, 0, stream>>>(X, linW, linb, logit0);
    k_interact<<<BATCH, 64, 0, stream>>>(sidx, emb, pW, outW, p1);
    k_dnn<<<BATCH / 64, 256, 0, stream>>>(X, sidx, emb, pW1, b1, pW2, b2, outW,
                                          logit0, p1, out);
}